// Round 1
// baseline (311.905 us; speedup 1.0000x reference)
//
#include <hip/hip_runtime.h>
#include <math.h>

#define GTMAX 64
#define KMAX 1024
#define MS 28
#define MSQ (MS*MS)

// ---------- helpers ----------
// IoU with pinned IEEE ops: must be bit-identical between pass1 and pass2
// (force_pos uses float equality against the per-gt max).
__device__ __forceinline__ float iou_f(float4 a, float areaA, float4 b, float areaB) {
    float lx = fmaxf(a.x, b.x), ly = fmaxf(a.y, b.y);
    float rx = fminf(a.z, b.z), ry = fminf(a.w, b.w);
    float w = fmaxf(__fsub_rn(rx, lx), 0.0f);
    float h = fmaxf(__fsub_rn(ry, ly), 0.0f);
    float inter = __fmul_rn(w, h);
    float den = __fsub_rn(__fadd_rn(areaA, areaB), inter);
    return __fdiv_rn(inter, den);
}

__device__ __forceinline__ float box_area(float4 b) {
    return __fmul_rn(__fsub_rn(b.z, b.x), __fsub_rn(b.w, b.y));
}

__device__ __forceinline__ float sl1(float x) {
    float ax = fabsf(x);
    return ax < 1.0f ? 0.5f * ax * ax : ax - 0.5f;
}

__device__ __forceinline__ float bce(float l, float t) {
    return fmaxf(l, 0.0f) - l * t + log1pf(expf(-fabsf(l)));
}

// acc layout: 0 rpn_ce, 1 rpn_valid, 2 rpn_reg, 3 rpn_pos,
//             4 det_ce, 5 det_sel, 6 det_reg, 7 det_selfg,
//             8 vis_sum, 9 amo_sum, 10 keep_cnt
__global__ void k_init(unsigned* gmax, float* acc) {
    int t = threadIdx.x;
    if (t < GTMAX) gmax[t] = 0u;
    if (t < 16) acc[t] = 0.0f;
}

// ---------- RPN pass 1: per-gt max IoU over all anchors ----------
__global__ void k_rpn_pass1(const float4* __restrict__ anchors, const float4* __restrict__ gt,
                            int N, int M, unsigned* gmax) {
    __shared__ float4 sgt[GTMAX];
    __shared__ float sarea[GTMAX];
    __shared__ unsigned smax[GTMAX];
    int t = threadIdx.x;
    if (t < M) {
        float4 b = gt[t];
        sgt[t] = b;
        sarea[t] = box_area(b);
        smax[t] = 0u;
    }
    __syncthreads();
    int i = blockIdx.x * blockDim.x + t;
    bool act = i < N;
    float4 a = make_float4(0.f, 0.f, 1.f, 1.f);
    float areaA = 1.0f;
    if (act) { a = anchors[i]; areaA = box_area(a); }
    for (int j = 0; j < M; ++j) {
        float v = act ? iou_f(a, areaA, sgt[j], sarea[j]) : 0.0f;
        // wave max (64 lanes)
        for (int off = 32; off; off >>= 1) v = fmaxf(v, __shfl_xor(v, off));
        if ((t & 63) == 0) atomicMax(&smax[j], __float_as_uint(v));
    }
    __syncthreads();
    if (t < M) atomicMax(&gmax[t], smax[t]);
}

// ---------- RPN pass 2: labels, cls loss, reg loss ----------
__global__ void k_rpn_pass2(const float4* __restrict__ anchors, const float4* __restrict__ preds,
                            const float2* __restrict__ cls, const float4* __restrict__ gt,
                            int N, int M, const unsigned* __restrict__ gmax, float* acc) {
    __shared__ float4 sgt[GTMAX];
    __shared__ float sarea[GTMAX];
    __shared__ float smaxpg[GTMAX];
    __shared__ float sacc[4];
    int t = threadIdx.x;
    if (t < M) {
        float4 b = gt[t];
        sgt[t] = b;
        sarea[t] = box_area(b);
        smaxpg[t] = __uint_as_float(gmax[t]);
    }
    if (t < 4) sacc[t] = 0.0f;
    __syncthreads();
    int i = blockIdx.x * blockDim.x + t;
    float ce_v = 0.f, valid = 0.f, pos = 0.f, reg = 0.f;
    if (i < N) {
        float4 a = anchors[i];
        float areaA = box_area(a);
        float maxiou = -1.0f;
        int arg = 0;
        bool force = false;
        for (int j = 0; j < M; ++j) {
            float v = iou_f(a, areaA, sgt[j], sarea[j]);
            if (v > maxiou) { maxiou = v; arg = j; }   // first-max (argmax semantics)
            force = force || (v == smaxpg[j]);
        }
        int label = force ? 1 : (maxiou >= 0.7f ? 1 : (maxiou <= 0.3f ? 0 : -1));
        if (label >= 0) {
            valid = 1.0f;
            float2 x = cls[i];
            float m = fmaxf(x.x, x.y);
            float lse = m + logf(expf(x.x - m) + expf(x.y - m));
            float lp = (label == 1 ? x.y : x.x) - lse;
            ce_v = -lp;
        }
        if (label == 1) {
            pos = 1.0f;
            float4 g = sgt[arg];
            float rw = a.z - a.x, rh = a.w - a.y;
            float t0 = ((g.x + g.z) * 0.5f - (a.x + a.z) * 0.5f) / rw;
            float t1 = ((g.y + g.w) * 0.5f - (a.y + a.w) * 0.5f) / rh;
            float t2 = logf((g.z - g.x) / rw);
            float t3 = logf((g.w - g.y) / rh);
            float4 p = preds[i];
            reg = sl1(p.x - t0) + sl1(p.y - t1) + sl1(p.z - t2) + sl1(p.w - t3);
        }
    }
    for (int off = 32; off; off >>= 1) {
        ce_v += __shfl_xor(ce_v, off);
        valid += __shfl_xor(valid, off);
        pos += __shfl_xor(pos, off);
        reg += __shfl_xor(reg, off);
    }
    if ((t & 63) == 0) {
        atomicAdd(&sacc[0], ce_v);
        atomicAdd(&sacc[1], valid);
        atomicAdd(&sacc[2], pos);
        atomicAdd(&sacc[3], reg);
    }
    __syncthreads();
    if (t == 0) {
        atomicAdd(&acc[0], sacc[0]);
        atomicAdd(&acc[1], sacc[1]);
        atomicAdd(&acc[3], sacc[2]);
        atomicAdd(&acc[2], sacc[3]);
    }
}

// ---------- Detection head: matching, sampling, cls+reg loss ----------
__global__ void k_det(const float4* __restrict__ proposals, const float4* __restrict__ gt,
                      const int* __restrict__ gt_labels, const float* __restrict__ cls,
                      const float* __restrict__ deltas, int K, int M, int C,
                      float* acc, int* g_gidx, int* g_keep) {
    __shared__ float4 sgt[GTMAX];
    __shared__ float sarea[GTMAX];
    __shared__ int slab[GTMAX];
    __shared__ float smiou[KMAX];
    __shared__ int sgi[KMAX];
    __shared__ int spl[KMAX];
    __shared__ unsigned char sfg[KMAX], sbg[KMAX];
    __shared__ float sacc[5];
    int t = threadIdx.x;
    if (t < M) {
        float4 b = gt[t];
        sgt[t] = b;
        sarea[t] = box_area(b);
        slab[t] = gt_labels[t];
    }
    if (t < 5) sacc[t] = 0.0f;
    __syncthreads();
    for (int p = t; p < K; p += blockDim.x) {
        float4 a = proposals[p];
        float areaA = box_area(a);
        float mx = -1.0f;
        int am = 0;
        for (int j = 0; j < M; ++j) {
            float v = iou_f(a, areaA, sgt[j], sarea[j]);
            if (v > mx) { mx = v; am = j; }
        }
        smiou[p] = mx;
        sgi[p] = am;
        int pl = slab[am];
        if (mx < 0.5f) pl = 0;
        if (mx < 0.1f) pl = -1;
        spl[p] = pl;
    }
    __syncthreads();
    if (t == 0) {  // sequential cumsum selection (inherently serial, K=1000)
        int fgtot = 0;
        for (int p = 0; p < K; ++p) fgtot += (spl[p] > 0);
        int nfg = fgtot < 32 ? fgtot : 32;
        int nbg = 128 - nfg;
        int cf = 0, cb = 0;
        for (int p = 0; p < K; ++p) {
            bool fg = spl[p] > 0, bg = spl[p] == 0;
            cf += fg; cb += bg;
            sfg[p] = (unsigned char)(fg && cf <= nfg);
            sbg[p] = (unsigned char)(bg && cb <= nbg);
        }
    }
    __syncthreads();
    float ce_s = 0.f, sel_c = 0.f, reg_s = 0.f, fg_c = 0.f, keep_c = 0.f;
    for (int p = t; p < K; p += blockDim.x) {
        bool self = sfg[p] != 0, selb = sbg[p] != 0;
        int lab = spl[p] > 0 ? spl[p] : 0;
        if (self || selb) {
            const float* row = cls + (size_t)p * C;
            float m = row[0];
            for (int c = 1; c < C; ++c) m = fmaxf(m, row[c]);
            float s = 0.f;
            for (int c = 0; c < C; ++c) s += expf(row[c] - m);
            float lse = m + logf(s);
            ce_s += -(row[lab] - lse);
            sel_c += 1.0f;
        }
        if (self) {
            fg_c += 1.0f;
            float4 a = proposals[p];
            float4 g = sgt[sgi[p]];
            float rw = a.z - a.x, rh = a.w - a.y;
            float t0 = ((g.x + g.z) * 0.5f - (a.x + a.z) * 0.5f) / rw;
            float t1 = ((g.y + g.w) * 0.5f - (a.y + a.w) * 0.5f) / rh;
            float t2 = logf((g.z - g.x) / rw);
            float t3 = logf((g.w - g.y) / rh);
            const float* pr = deltas + ((size_t)p * C + lab) * 4;
            reg_s += sl1(pr[0] - t0) + sl1(pr[1] - t1) + sl1(pr[2] - t2) + sl1(pr[3] - t3);
        }
        int kp = smiou[p] >= 0.5f ? 1 : 0;
        keep_c += (float)kp;
        g_gidx[p] = sgi[p];
        g_keep[p] = kp;
    }
    for (int off = 32; off; off >>= 1) {
        ce_s += __shfl_xor(ce_s, off);
        sel_c += __shfl_xor(sel_c, off);
        reg_s += __shfl_xor(reg_s, off);
        fg_c += __shfl_xor(fg_c, off);
        keep_c += __shfl_xor(keep_c, off);
    }
    if ((t & 63) == 0) {
        atomicAdd(&sacc[0], ce_s);
        atomicAdd(&sacc[1], sel_c);
        atomicAdd(&sacc[2], reg_s);
        atomicAdd(&sacc[3], fg_c);
        atomicAdd(&sacc[4], keep_c);
    }
    __syncthreads();
    if (t == 0) {  // single block, stream-ordered after init: direct store OK
        acc[4] = sacc[0];
        acc[5] = sacc[1];
        acc[6] = sacc[2];
        acc[7] = sacc[3];
        acc[10] = sacc[4];
    }
}

// ---------- Mask loss: only keep (miou>=0.5) proposals contribute ----------
__global__ void k_mask(const float* __restrict__ vism, const float* __restrict__ amom,
                       const float* __restrict__ lv_all, const float* __restrict__ la_all,
                       const float4* __restrict__ proposals, const int* __restrict__ gidx,
                       const int* __restrict__ keepf, const int* __restrict__ gt_labels,
                       int C, int H, float* acc) {
    int p = blockIdx.x;
    if (!keepf[p]) return;
    int gi = gidx[p];
    int lab = gt_labels[gi];
    float4 r = proposals[p];
    float x1 = r.x - 0.5f, y1 = r.y - 0.5f;
    float bw = (r.z - r.x) / (float)MS;
    float bh = (r.w - r.y) / (float)MS;
    const float* vm = vism + (size_t)gi * H * H;
    const float* am = amom + (size_t)gi * H * H;
    const float* lv = lv_all + ((size_t)p * C + lab) * MSQ;
    const float* la = la_all + ((size_t)p * C + lab) * MSQ;
    float sv = 0.f, sa = 0.f;
    for (int px = threadIdx.x; px < MSQ; px += blockDim.x) {
        int gx = px % MS, gy = px / MS;
        float X = x1 + ((float)gx + 0.5f) * bw;
        float Y = y1 + ((float)gy + 0.5f) * bh;
        bool valid = (Y > -1.0f) && (Y < (float)H) && (X > -1.0f) && (X < (float)H);
        float Yc = fminf(fmaxf(Y, 0.0f), (float)(H - 1));
        float Xc = fminf(fmaxf(X, 0.0f), (float)(H - 1));
        int y0 = (int)floorf(Yc), x0 = (int)floorf(Xc);
        int y1i = min(y0 + 1, H - 1), x1i = min(x0 + 1, H - 1);
        float ly = Yc - (float)y0, lx = Xc - (float)x0;
        float w00 = (1.f - ly) * (1.f - lx), w01 = (1.f - ly) * lx;
        float w10 = ly * (1.f - lx), w11 = ly * lx;
        float tv = vm[y0 * H + x0] * w00 + vm[y0 * H + x1i] * w01 +
                   vm[y1i * H + x0] * w10 + vm[y1i * H + x1i] * w11;
        float ta = am[y0 * H + x0] * w00 + am[y0 * H + x1i] * w01 +
                   am[y1i * H + x0] * w10 + am[y1i * H + x1i] * w11;
        if (!valid) { tv = 0.f; ta = 0.f; }
        sv += bce(lv[px], tv);
        sa += bce(la[px], ta);
    }
    __shared__ float sred[2];
    if (threadIdx.x < 2) sred[threadIdx.x] = 0.f;
    __syncthreads();
    for (int off = 32; off; off >>= 1) {
        sv += __shfl_xor(sv, off);
        sa += __shfl_xor(sa, off);
    }
    if ((threadIdx.x & 63) == 0) {
        atomicAdd(&sred[0], sv);
        atomicAdd(&sred[1], sa);
    }
    __syncthreads();
    if (threadIdx.x == 0) {
        atomicAdd(&acc[8], sred[0]);
        atomicAdd(&acc[9], sred[1]);
    }
}

__global__ void k_final(const float* acc, float* out) {
    float rpn_cls = acc[0] / fmaxf(acc[1], 1.0f);
    float rpn_reg = acc[2] / fmaxf(acc[3] * 4.0f, 1.0f);
    float det_cls = acc[4] / fmaxf(acc[5], 1.0f);
    float det_reg = acc[6] / fmaxf(acc[7] * 4.0f, 1.0f);
    float denom = fmaxf(acc[10], 1.0f) * (float)MSQ;
    float mask = acc[8] / denom + acc[9] / denom;
    out[0] = rpn_cls + rpn_reg + det_cls + det_reg + mask;
}

extern "C" void kernel_launch(void* const* d_in, const int* in_sizes, int n_in,
                              void* d_out, int out_size, void* d_ws, size_t ws_size,
                              hipStream_t stream) {
    const float2* rpn_cls = (const float2*)d_in[0];
    const float4* rpn_pred = (const float4*)d_in[1];
    const float4* anchors = (const float4*)d_in[2];
    const float4* gt = (const float4*)d_in[3];
    const int* gt_labels = (const int*)d_in[4];
    const float* roi_cls = (const float*)d_in[5];
    const float* roi_deltas = (const float*)d_in[6];
    const float4* proposals = (const float4*)d_in[7];
    const float* mvl = (const float*)d_in[8];
    const float* mal = (const float*)d_in[9];
    const float* vism = (const float*)d_in[10];
    const float* amom = (const float*)d_in[11];

    int N = in_sizes[0] / 2;
    int M = in_sizes[3] / 4;
    int K = in_sizes[7] / 4;
    int C = in_sizes[5] / K;
    int HW = in_sizes[10] / M;
    int H = (int)(sqrt((double)HW) + 0.5);

    unsigned* gmax = (unsigned*)d_ws;              // 64 u32
    float* acc = (float*)d_ws + 64;                // 16 f32
    int* g_gidx = (int*)d_ws + 96;                 // K ints
    int* g_keep = g_gidx + K;                      // K ints
    float* out = (float*)d_out;

    k_init<<<1, 64, 0, stream>>>(gmax, acc);
    int nb = (N + 255) / 256;
    k_rpn_pass1<<<nb, 256, 0, stream>>>(anchors, gt, N, M, gmax);
    k_rpn_pass2<<<nb, 256, 0, stream>>>(anchors, rpn_pred, rpn_cls, gt, N, M, gmax, acc);
    k_det<<<1, 256, 0, stream>>>(proposals, gt, gt_labels, roi_cls, roi_deltas, K, M, C,
                                 acc, g_gidx, g_keep);
    k_mask<<<K, 256, 0, stream>>>(vism, amom, mvl, mal, proposals, g_gidx, g_keep,
                                  gt_labels, C, H, acc);
    k_final<<<1, 1, 0, stream>>>(acc, out);
}